// Round 1
// baseline (1121.572 us; speedup 1.0000x reference)
//
#include <hip/hip_runtime.h>

// ---------------- problem constants ----------------
#define NBATCH 32
#define LSEQ   2048
#define CDIM   256
#define KDIM   1024
#define DEMI   8
#define H1DIM  40
#define DEMO   20
#define NCHUNK 32
#define CHLEN  64
#define LNEPS  1e-5f

// ---- ws layout (float element offsets) ----
#define OFF_X    0L            // 32*2048*256 = 16777216  (X, overwritten in-place by p_max)
#define OFF_S    16777216L     // cumsum, 16777216
#define OFF_AGM  33554432L     // 32*32*256 = 262144
#define OFF_AGS  33816576L
#define OFF_AGI  34078720L     // int
#define OFF_PRM  34340864L
#define OFF_PRS  34603008L
#define OFF_PRI  34865152L     // int
#define OFF_DV   35127296L     // 32*20
#define OFF_BASE 35127936L     // 32*256
// total 35136128 floats = 140.5 MB

// ---- d_out sections (float element offsets) ----
#define OUT0_OFF   0L          // [32,2048,788]
#define OUTTI_OFF  51642368L   // [32,256,2048]
#define OUTACT_OFF 68419584L   // [32,256,2048]

// ---------------------------------------------------------------------------
// K1: dem MLP (8->40->20, ReLU) + fold dem & b_lin into per-(n,c) base
// ---------------------------------------------------------------------------
__global__ __launch_bounds__(256) void k_dem(
    const float* __restrict__ dem,
    const float* __restrict__ W1, const float* __restrict__ b1,
    const float* __restrict__ W2, const float* __restrict__ b2,
    const float* __restrict__ Wl, const float* __restrict__ bl,
    float* __restrict__ dvals, float* __restrict__ base)
{
    __shared__ float h1[NBATCH][H1DIM];
    __shared__ float dsh[NBATCH][DEMO];
    int tid = threadIdx.x;

    for (int idx = tid; idx < NBATCH * H1DIM; idx += 256) {
        int n = idx / H1DIM, o = idx % H1DIM;
        float s = b1[o];
        #pragma unroll
        for (int k = 0; k < DEMI; ++k) s += dem[n * DEMI + k] * W1[k * H1DIM + o];
        h1[n][o] = fmaxf(s, 0.0f);
    }
    __syncthreads();
    for (int idx = tid; idx < NBATCH * DEMO; idx += 256) {
        int n = idx / DEMO, o = idx % DEMO;
        float s = b2[o];
        #pragma unroll
        for (int k = 0; k < H1DIM; ++k) s += h1[n][k] * W2[k * DEMO + o];
        float dv = fmaxf(s, 0.0f);
        dsh[n][o] = dv;
        dvals[idx] = dv;
    }
    __syncthreads();
    for (int idx = tid; idx < NBATCH * CDIM; idx += 256) {
        int n = idx >> 8, c = idx & 255;
        float s = bl[c];
        #pragma unroll
        for (int k = 0; k < DEMO; ++k) s += dsh[n][k] * Wl[(KDIM + k) * CDIM + c];
        base[idx] = s;
    }
}

// ---------------------------------------------------------------------------
// K2: fp32 GEMM  X[n,t,c] = sum_j ts[n,t,j] * W[j,c] + base[n,c]
//     M=65536 (n,t), N=256, K=1024. Block tile BM=64 x BN=256 (full width ->
//     each A element fetched from HBM exactly once), BK=32.
//     256 threads, 16x16 grid, 4x16 micro-tile per thread.
// ---------------------------------------------------------------------------
__global__ __launch_bounds__(256) void k_gemm(
    const float* __restrict__ ts0, const float* __restrict__ ts1,
    const float* __restrict__ ts2, const float* __restrict__ ts3,
    const float* __restrict__ W, const float* __restrict__ base,
    float* __restrict__ X)
{
    __shared__ float As[32][64];    // [k][m] transposed
    __shared__ float Bs[32][256];   // [k][c]

    int tid = threadIdx.x;
    int n  = blockIdx.x >> 5;
    int t0 = (blockIdx.x & 31) << 6;
    int tm = tid & 15;          // m group: rows tm*4 .. tm*4+3
    int tn = tid >> 4;          // c group: cols tn*16 .. tn*16+15

    float acc[4][16];
    #pragma unroll
    for (int i = 0; i < 4; ++i)
        #pragma unroll
        for (int j = 0; j < 16; ++j) acc[i][j] = 0.0f;

    const long rowbase = ((long)n * LSEQ + t0) * CDIM;

    int lm = tid >> 3;          // 0..31 (A load row)
    int lkg = tid & 7;          // 0..7  (A load k-group of 4)

    for (int k0 = 0; k0 < KDIM; k0 += 32) {
        const float* tsp = (k0 < 256) ? ts0 : (k0 < 512) ? ts1 : (k0 < 768) ? ts2 : ts3;
        int joff = k0 & 255;

        // prefetch A tile (64 rows x 32 k) into regs
        float4 av0 = *(const float4*)(tsp + rowbase + (long)lm * CDIM + joff + lkg * 4);
        float4 av1 = *(const float4*)(tsp + rowbase + (long)(lm + 32) * CDIM + joff + lkg * 4);
        // prefetch B tile (32 k x 256 c)
        float4 bv[8];
        #pragma unroll
        for (int r = 0; r < 8; ++r) {
            int idx = tid + r * 256;
            int kk = idx >> 6, cg = idx & 63;
            bv[r] = *(const float4*)(W + (long)(k0 + kk) * CDIM + cg * 4);
        }

        __syncthreads();   // previous tile fully consumed
        As[lkg * 4 + 0][lm] = av0.x;
        As[lkg * 4 + 1][lm] = av0.y;
        As[lkg * 4 + 2][lm] = av0.z;
        As[lkg * 4 + 3][lm] = av0.w;
        As[lkg * 4 + 0][lm + 32] = av1.x;
        As[lkg * 4 + 1][lm + 32] = av1.y;
        As[lkg * 4 + 2][lm + 32] = av1.z;
        As[lkg * 4 + 3][lm + 32] = av1.w;
        #pragma unroll
        for (int r = 0; r < 8; ++r) {
            int idx = tid + r * 256;
            int kk = idx >> 6, cg = idx & 63;
            *(float4*)&Bs[kk][cg * 4] = bv[r];
        }
        __syncthreads();

        #pragma unroll 8
        for (int kk = 0; kk < 32; ++kk) {
            float4 a  = *(const float4*)&As[kk][tm * 4];
            float4 b0 = *(const float4*)&Bs[kk][tn * 16 + 0];
            float4 b1 = *(const float4*)&Bs[kk][tn * 16 + 4];
            float4 b2 = *(const float4*)&Bs[kk][tn * 16 + 8];
            float4 b3 = *(const float4*)&Bs[kk][tn * 16 + 12];
            const float am[4] = {a.x, a.y, a.z, a.w};
            const float bc[16] = {b0.x, b0.y, b0.z, b0.w, b1.x, b1.y, b1.z, b1.w,
                                  b2.x, b2.y, b2.z, b2.w, b3.x, b3.y, b3.z, b3.w};
            #pragma unroll
            for (int mi = 0; mi < 4; ++mi)
                #pragma unroll
                for (int j = 0; j < 16; ++j)
                    acc[mi][j] = fmaf(am[mi], bc[j], acc[mi][j]);
        }
    }

    // epilogue: add base, write X
    float bb[16];
    #pragma unroll
    for (int j = 0; j < 16; ++j) bb[j] = base[n * CDIM + tn * 16 + j];

    #pragma unroll
    for (int mi = 0; mi < 4; ++mi) {
        long row = rowbase + (long)(tm * 4 + mi) * CDIM;
        #pragma unroll
        for (int e = 0; e < 4; ++e) {
            float4 v;
            v.x = acc[mi][e * 4 + 0] + bb[e * 4 + 0];
            v.y = acc[mi][e * 4 + 1] + bb[e * 4 + 1];
            v.z = acc[mi][e * 4 + 2] + bb[e * 4 + 2];
            v.w = acc[mi][e * 4 + 3] + bb[e * 4 + 3];
            *(float4*)(X + row + tn * 16 + e * 4) = v;
        }
    }
}

// ---------------------------------------------------------------------------
// K3a: per-chunk aggregates (max + first-argmax + sum) over 64 t's
// ---------------------------------------------------------------------------
__global__ __launch_bounds__(256) void k_agg(
    const float* __restrict__ X,
    float* __restrict__ agm, float* __restrict__ ags, int* __restrict__ agi)
{
    int c = threadIdx.x;
    int n = blockIdx.x >> 5, ch = blockIdx.x & 31;
    int t0 = ch * CHLEN;
    const float* p = X + ((long)n * LSEQ + t0) * CDIM + c;
    float vm = -3.4e38f; int im = t0; float sm = 0.0f;
    #pragma unroll 4
    for (int tt = 0; tt < CHLEN; ++tt) {
        float v = p[(long)tt * CDIM];
        if (v > vm) { vm = v; im = t0 + tt; }
        sm += v;
    }
    int o = (n * NCHUNK + ch) * CDIM + c;
    agm[o] = vm; ags[o] = sm; agi[o] = im;
}

// ---------------------------------------------------------------------------
// K3b: exclusive prefix over chunks per (n,c)
// ---------------------------------------------------------------------------
__global__ __launch_bounds__(256) void k_pre(
    const float* __restrict__ agm, const float* __restrict__ ags, const int* __restrict__ agi,
    float* __restrict__ prm, float* __restrict__ prs, int* __restrict__ pri)
{
    int c = threadIdx.x;
    int n = blockIdx.x;
    float vm = -3.4e38f; int im = 0; float sm = 0.0f;
    for (int ch = 0; ch < NCHUNK; ++ch) {
        int o = (n * NCHUNK + ch) * CDIM + c;
        prm[o] = vm; pri[o] = im; prs[o] = sm;
        float av = agm[o]; float as = ags[o]; int ai = agi[o];
        if (av > vm) { vm = av; im = ai; }   // earlier chunk wins ties (av must be strictly >)
        sm += as;
    }
}

// ---------------------------------------------------------------------------
// K3c: final scan. Writes p_max_raw (in-place over X), cumsum S, and
//      time_inds (as float) into Ttmp ([n,t,c] order, staged in d_out act section)
// ---------------------------------------------------------------------------
__global__ __launch_bounds__(256) void k_scan(
    float* __restrict__ X, float* __restrict__ S,
    const float* __restrict__ prm, const float* __restrict__ prs, const int* __restrict__ pri,
    float* __restrict__ Ttmp)
{
    int c = threadIdx.x;
    int n = blockIdx.x >> 5, ch = blockIdx.x & 31;
    int t0 = ch * CHLEN;
    int o = (n * NCHUNK + ch) * CDIM + c;
    float vm = prm[o]; int im = pri[o]; float sm = prs[o];
    long rb = ((long)n * LSEQ + t0) * CDIM + c;
    #pragma unroll 4
    for (int tt = 0; tt < CHLEN; ++tt) {
        int t = t0 + tt;
        long idx = rb + (long)tt * CDIM;
        float v = X[idx];
        if (v > vm) { vm = v; im = t; }
        sm += v;
        bool pad = t < (LSEQ - 1);
        float pm = pad ? fmaxf(vm, 0.0f) : vm;
        int ti = (pad && vm <= 0.0f) ? (t - (LSEQ - 1)) : im;
        X[idx] = pm;
        S[idx] = sm;
        Ttmp[idx] = (float)ti;
    }
}

// ---------------------------------------------------------------------------
// K5: tiled transpose per n: [n, t, c] (2048x256) -> [n, c, t] (256x2048)
// ---------------------------------------------------------------------------
__global__ __launch_bounds__(256) void k_tr(
    const float* __restrict__ src, float* __restrict__ dst)
{
    __shared__ float tile[64][65];
    int n  = blockIdx.z;
    int tB = blockIdx.x;   // 0..31
    int cB = blockIdx.y;   // 0..3
    int tid = threadIdx.x;
    int i0 = tid >> 4;     // 0..15
    int j4 = tid & 15;     // 0..15

    const float* sp = src + ((long)n * LSEQ + tB * 64) * CDIM + cB * 64;
    #pragma unroll
    for (int r = 0; r < 4; ++r) {
        int i = i0 + r * 16;
        float4 v = *(const float4*)(sp + (long)i * CDIM + j4 * 4);
        tile[i][j4 * 4 + 0] = v.x;
        tile[i][j4 * 4 + 1] = v.y;
        tile[i][j4 * 4 + 2] = v.z;
        tile[i][j4 * 4 + 3] = v.w;
    }
    __syncthreads();
    float* dp = dst + ((long)n * CDIM + cB * 64) * LSEQ + tB * 64;
    #pragma unroll
    for (int r = 0; r < 4; ++r) {
        int j = i0 + r * 16;   // c within tile
        float4 v;
        v.x = tile[j4 * 4 + 0][j];
        v.y = tile[j4 * 4 + 1][j];
        v.z = tile[j4 * 4 + 2][j];
        v.w = tile[j4 * 4 + 3][j];
        *(float4*)(dp + (long)j * LSEQ + j4 * 4) = v;
    }
}

// ---------------------------------------------------------------------------
// K4: LayerNorm over c for p_max / p_avg / p_sum + dem tail -> out0 [n,t,788]
//     One 64-lane wave per (n,t) row; 4 channels per lane; shuffle reductions.
//     LN(csum*a) = (csum - mu_s) * a / sqrt(a^2 var_s + eps)  (per-row scalar a)
// ---------------------------------------------------------------------------
__global__ __launch_bounds__(256) void k_ln(
    const float* __restrict__ P, const float* __restrict__ S,
    const float* __restrict__ dvals, float* __restrict__ out0)
{
    int tid = threadIdx.x;
    int wid = tid >> 6, lane = tid & 63;
    long row = (long)blockIdx.x * 4 + wid;  // 0..65535
    int n = (int)(row >> 11);
    int t = (int)(row & 2047);
    long ib = row * CDIM + lane * 4;

    float4 p = *(const float4*)(P + ib);
    float4 s = *(const float4*)(S + ib);

    float sum_p = p.x + p.y + p.z + p.w;
    float sq_p  = p.x * p.x + p.y * p.y + p.z * p.z + p.w * p.w;
    float sum_s = s.x + s.y + s.z + s.w;
    float sq_s  = s.x * s.x + s.y * s.y + s.z * s.z + s.w * s.w;

    #pragma unroll
    for (int off = 32; off > 0; off >>= 1) {
        sum_p += __shfl_xor(sum_p, off);
        sq_p  += __shfl_xor(sq_p, off);
        sum_s += __shfl_xor(sum_s, off);
        sq_s  += __shfl_xor(sq_s, off);
    }

    const float inv = 1.0f / 256.0f;
    float mu_p = sum_p * inv;
    float var_p = sq_p * inv - mu_p * mu_p;
    float mu_s = sum_s * inv;
    float var_s = sq_s * inv - mu_s * mu_s;

    float r1 = 1.0f / sqrtf(var_p + LNEPS);
    const float a = 1.0f / 2048.0f;
    float r2 = a / sqrtf(a * a * var_s + LNEPS);
    float b = 1.0f / sqrtf((float)(t + 1));
    float r3 = b / sqrtf(b * b * var_s + LNEPS);

    float* ob = out0 + row * 788;
    float4 o1 = {(p.x - mu_p) * r1, (p.y - mu_p) * r1, (p.z - mu_p) * r1, (p.w - mu_p) * r1};
    *(float4*)(ob + lane * 4) = o1;
    float4 o2 = {(s.x - mu_s) * r2, (s.y - mu_s) * r2, (s.z - mu_s) * r2, (s.w - mu_s) * r2};
    *(float4*)(ob + 256 + lane * 4) = o2;
    float4 o3 = {(s.x - mu_s) * r3, (s.y - mu_s) * r3, (s.z - mu_s) * r3, (s.w - mu_s) * r3};
    *(float4*)(ob + 512 + lane * 4) = o3;
    if (lane < 5) {
        float4 dv = *(const float4*)(dvals + n * DEMO + lane * 4);
        *(float4*)(ob + 768 + lane * 4) = dv;
    }
}

// ---------------------------------------------------------------------------
extern "C" void kernel_launch(void* const* d_in, const int* in_sizes, int n_in,
                              void* d_out, int out_size, void* d_ws, size_t ws_size,
                              hipStream_t stream)
{
    const float* dem = (const float*)d_in[0];
    const float* ts0 = (const float*)d_in[1];
    const float* ts1 = (const float*)d_in[2];
    const float* ts2 = (const float*)d_in[3];
    const float* ts3 = (const float*)d_in[4];
    const float* W1  = (const float*)d_in[5];
    const float* b1  = (const float*)d_in[6];
    const float* W2  = (const float*)d_in[7];
    const float* b2  = (const float*)d_in[8];
    const float* Wl  = (const float*)d_in[9];
    const float* bl  = (const float*)d_in[10];

    float* ws = (float*)d_ws;
    float* X    = ws + OFF_X;
    float* S    = ws + OFF_S;
    float* agm  = ws + OFF_AGM;
    float* ags  = ws + OFF_AGS;
    int*   agi  = (int*)(ws + OFF_AGI);
    float* prm  = ws + OFF_PRM;
    float* prs  = ws + OFF_PRS;
    int*   pri  = (int*)(ws + OFF_PRI);
    float* dv   = ws + OFF_DV;
    float* base = ws + OFF_BASE;

    float* out    = (float*)d_out;
    float* outTI  = out + OUTTI_OFF;
    float* outACT = out + OUTACT_OFF;

    k_dem<<<1, 256, 0, stream>>>(dem, W1, b1, W2, b2, Wl, bl, dv, base);
    k_gemm<<<NBATCH * 32, 256, 0, stream>>>(ts0, ts1, ts2, ts3, Wl, base, X);
    k_agg<<<NBATCH * NCHUNK, 256, 0, stream>>>(X, agm, ags, agi);
    k_pre<<<NBATCH, 256, 0, stream>>>(agm, ags, agi, prm, prs, pri);
    // Ttmp staged in the activations section of d_out ([n,t,c] order)
    k_scan<<<NBATCH * NCHUNK, 256, 0, stream>>>(X, S, prm, prs, pri, outACT);
    // transpose time_inds: Ttmp [n,t,c] -> outTI [n,c,t]
    k_tr<<<dim3(32, 4, 32), 256, 0, stream>>>(outACT, outTI);
    // transpose activations: P (=X after scan) [n,t,c] -> outACT [n,c,t]
    k_tr<<<dim3(32, 4, 32), 256, 0, stream>>>(X, outACT);
    // LN + concat + dem tail -> out0
    k_ln<<<16384, 256, 0, stream>>>(X, S, dv, out);
}